// Round 1
// baseline (163.174 us; speedup 1.0000x reference)
//
#include <hip/hip_runtime.h>

#define NEG_INF (-__builtin_inff())

typedef float v2f __attribute__((ext_vector_type(2)));

// Guaranteed packed-f32 add (gfx90a+/gfx950 VOP3P). Two adds in one issue slot.
static __device__ __forceinline__ v2f pk_add(v2f a, v2f b) {
    v2f d;
    asm("v_pk_add_f32 %0, %1, %2" : "=v"(d) : "v"(a), "v"(b));
    return d;
}

// Each thread: all Co=8 outputs for 8 consecutive w pixels at one (n,h).
// co paired (2p, 2p+1) in v2f accumulators -> v_pk_add_f32 for the 100 taps.
// Weights prepacked co-contiguous into LDS so a co-pair tap is one ds_read_b64.
// Block = 256 threads = 4 output rows x 64 w-groups. Grid = N * H/4 = 1024.
__global__ __launch_bounds__(256, 2) void dil2d_kernel(const float* __restrict__ x,
                                                       const float* __restrict__ w,
                                                       float* __restrict__ out) {
    const int Ci = 4, H = 512, W = 512;

    // LDS weight prepack: wl[ci][kh][kw][co]  (800 floats = 3.2 KB)
    __shared__ float wl[800];
    {
        int i = threadIdx.x;
#pragma unroll
        for (int rep = 0; rep < 4; ++rep, i += 256) {
            if (i < 800) {
                const int co = i & 7;
                const int t  = i >> 3;          // ci*25 + kh*5 + kw
                const int kw = t % 5;
                const int kh = (t / 5) % 5;
                const int ci = t / 25;
                wl[i] = w[((co * 4 + ci) * 5 + kh) * 5 + kw];
            }
        }
    }
    __syncthreads();

    const int tid = threadIdx.x;
    const int wg  = tid & 63;       // w-group 0..63
    const int w0  = wg << 3;        // 0..504
    const int rib = tid >> 6;       // row in block 0..3 (wave-uniform)
    const int b   = blockIdx.x;
    const int n   = b >> 7;         // / 128
    const int h   = ((b & 127) << 2) + rib;

    // acc for co-pair p: x half = co=2p, y half = co=2p+1
    float accx[4][8], accy[4][8];
#pragma unroll
    for (int p = 0; p < 4; ++p)
#pragma unroll
        for (int j = 0; j < 8; ++j) { accx[p][j] = NEG_INF; accy[p][j] = NEG_INF; }

    const float* xn = x + n * (Ci * H * W);

    for (int ci = 0; ci < Ci; ++ci) {
        const float* xc = xn + ci * (H * W);
        const v2f*   wc = (const v2f*)(wl + ci * 200);   // 100 pairs per ci
        for (int kh = 0; kh < 5; ++kh) {
            const int r = h + kh - 2;
            if (r < 0 || r >= H) continue;   // wave-uniform branch; -inf pad == skip
            const float* xr = xc + r * W;

            // window xv[0..11] = x[r][w0-2 .. w0+9], -inf outside image
            const int off_lo = (w0 == 0)   ? 0   : (w0 - 4);   // 16B aligned
            const int off_hi = (w0 == 504) ? 504 : (w0 + 8);   // 16B aligned
            const float4 lo4 = *(const float4*)(xr + off_lo);
            const float4 m0  = *(const float4*)(xr + w0);
            const float4 m1  = *(const float4*)(xr + w0 + 4);
            const float4 hi4 = *(const float4*)(xr + off_hi);

            float xv[12];
            xv[0]  = (w0 == 0)   ? NEG_INF : lo4.z;
            xv[1]  = (w0 == 0)   ? NEG_INF : lo4.w;
            xv[2]  = m0.x; xv[3] = m0.y; xv[4] = m0.z; xv[5] = m0.w;
            xv[6]  = m1.x; xv[7] = m1.y; xv[8] = m1.z; xv[9] = m1.w;
            xv[10] = (w0 == 504) ? NEG_INF : hi4.x;
            xv[11] = (w0 == 504) ? NEG_INF : hi4.y;

            // broadcast each window element once into a v2f pair
            v2f xb[12];
#pragma unroll
            for (int m = 0; m < 12; ++m) { v2f t; t.x = xv[m]; t.y = xv[m]; xb[m] = t; }

            const v2f* wk = wc + kh * 20;    // 5 kw x 4 co-pairs
#pragma unroll
            for (int p = 0; p < 4; ++p) {
                v2f w2[5];
#pragma unroll
                for (int k = 0; k < 5; ++k) w2[k] = wk[k * 4 + p];  // ds_read_b64, uniform
#pragma unroll
                for (int j = 0; j < 8; ++j) {
                    const v2f t0 = pk_add(xb[j],     w2[0]);
                    const v2f t1 = pk_add(xb[j + 1], w2[1]);
                    const v2f t2 = pk_add(xb[j + 2], w2[2]);
                    const v2f t3 = pk_add(xb[j + 3], w2[3]);
                    const v2f t4 = pk_add(xb[j + 4], w2[4]);
                    float ax = accx[p][j], ay = accy[p][j];
                    ax = fmaxf(ax, fmaxf(t0.x, t1.x));   // -> v_max3_f32
                    ay = fmaxf(ay, fmaxf(t0.y, t1.y));
                    ax = fmaxf(ax, fmaxf(t2.x, t3.x));
                    ay = fmaxf(ay, fmaxf(t2.y, t3.y));
                    ax = fmaxf(ax, t4.x);
                    ay = fmaxf(ay, t4.y);
                    accx[p][j] = ax; accy[p][j] = ay;
                }
            }
        }
    }

    float* on = out + n * (8 * H * W) + h * W + w0;
#pragma unroll
    for (int p = 0; p < 4; ++p) {
        const float4 a0 = make_float4(accx[p][0], accx[p][1], accx[p][2], accx[p][3]);
        const float4 a1 = make_float4(accx[p][4], accx[p][5], accx[p][6], accx[p][7]);
        const float4 b0 = make_float4(accy[p][0], accy[p][1], accy[p][2], accy[p][3]);
        const float4 b1 = make_float4(accy[p][4], accy[p][5], accy[p][6], accy[p][7]);
        float* o0 = on + (2 * p) * (H * W);
        float* o1 = o0 + (H * W);
        *(float4*)(o0)     = a0;
        *(float4*)(o0 + 4) = a1;
        *(float4*)(o1)     = b0;
        *(float4*)(o1 + 4) = b1;
    }
}

extern "C" void kernel_launch(void* const* d_in, const int* in_sizes, int n_in,
                              void* d_out, int out_size, void* d_ws, size_t ws_size,
                              hipStream_t stream) {
    const float* x = (const float*)d_in[0];
    const float* w = (const float*)d_in[1];
    float* out     = (float*)d_out;

    dim3 grid(1024), block(256);
    hipLaunchKernelGGL(dil2d_kernel, grid, block, 0, stream, x, w, out);
}

// Round 2
// 138.628 us; speedup vs baseline: 1.1771x; 1.1771x over previous
//
#include <hip/hip_runtime.h>

#define NEG_INF (-__builtin_inff())

// Each thread: 4 output channels x 8 consecutive w pixels at one (n,h).
// Scalar v_add_f32 + v_max3_f32 datapath (pk_add proven issue-neutral on CDNA4).
// Weights stay in the scalar path (uniform address via readfirstlane -> s_load).
// Block = 256 threads = 2 rows x 2 co-halves x 64 w-groups. Grid = N*H/2 = 2048.
// __launch_bounds__(256,4): 128-VGPR budget so acc lives in arch VGPRs
// (round-0's 32-VGPR allocation forced AGPR accvgpr_read/write shuttles).
__global__ __launch_bounds__(256, 4) void dil2d_kernel(const float* __restrict__ x,
                                                       const float* __restrict__ w,
                                                       float* __restrict__ out) {
    const int Ci = 4, H = 512, W = 512;

    const int tid = threadIdx.x;
    const int wg  = tid & 63;            // w-group 0..63 (one wave = one row segment)
    const int w0  = wg << 3;             // 0..504
    const int coh = (tid >> 6) & 1;      // co half, wave-uniform
    const int rib = tid >> 7;            // row in block 0..1, wave-uniform
    const int co0 = __builtin_amdgcn_readfirstlane(coh << 2);   // 0 or 4, SGPR
    const int b   = blockIdx.x;
    const int n   = b >> 8;
    const int h   = ((b & 255) << 1) + rib;

    float acc[4][8];
#pragma unroll
    for (int cs = 0; cs < 4; ++cs)
#pragma unroll
        for (int j = 0; j < 8; ++j) acc[cs][j] = NEG_INF;

    const float* xn = x + n * (Ci * H * W);

    const bool lo_edge = (w0 == 0);
    const bool hi_edge = (w0 == 504);
    const int  off_lo  = lo_edge ? 0   : (w0 - 4);   // 16B aligned
    const int  off_hi  = hi_edge ? 504 : (w0 + 8);   // 16B aligned

    for (int ci = 0; ci < Ci; ++ci) {
        const float* xc  = xn + ci * (H * W);
        const float* wci = w + co0 * (Ci * 25) + ci * 25;   // scalar address
        for (int kh = 0; kh < 5; ++kh) {
            const int r = h + kh - 2;
            if (r < 0 || r >= H) continue;   // wave-uniform; -inf pad == skip
            const float* xr = xc + r * W;

            // window xv[0..11] = x[r][w0-2 .. w0+9], -inf outside image
            const float4 lo4 = *(const float4*)(xr + off_lo);
            const float4 m0  = *(const float4*)(xr + w0);
            const float4 m1  = *(const float4*)(xr + w0 + 4);
            const float4 hi4 = *(const float4*)(xr + off_hi);

            float xv[12];
            xv[0]  = lo_edge ? NEG_INF : lo4.z;
            xv[1]  = lo_edge ? NEG_INF : lo4.w;
            xv[2]  = m0.x; xv[3] = m0.y; xv[4] = m0.z; xv[5] = m0.w;
            xv[6]  = m1.x; xv[7] = m1.y; xv[8] = m1.z; xv[9] = m1.w;
            xv[10] = hi_edge ? NEG_INF : hi4.x;
            xv[11] = hi_edge ? NEG_INF : hi4.y;

            const float* wk = wci + kh * 5;   // scalar -> s_load, off the VALU pipe
#pragma unroll
            for (int cs = 0; cs < 4; ++cs) {
                const float* wco = wk + cs * (Ci * 25);
                const float wv0 = wco[0], wv1 = wco[1], wv2 = wco[2],
                            wv3 = wco[3], wv4 = wco[4];
#pragma unroll
                for (int j = 0; j < 8; ++j) {
                    float m  = acc[cs][j];
                    float t0 = xv[j]     + wv0;
                    float t1 = xv[j + 1] + wv1;
                    m = fmaxf(m, fmaxf(t0, t1));          // -> v_max3_f32
                    float t2 = xv[j + 2] + wv2;
                    float t3 = xv[j + 3] + wv3;
                    m = fmaxf(m, fmaxf(t2, t3));          // -> v_max3_f32
                    m = fmaxf(m, xv[j + 4] + wv4);
                    acc[cs][j] = m;
                }
            }
        }
    }

    float* on = out + n * (8 * H * W) + (co0) * (H * W) + h * W + w0;
#pragma unroll
    for (int cs = 0; cs < 4; ++cs) {
        float* o = on + cs * (H * W);
        *(float4*)(o)     = make_float4(acc[cs][0], acc[cs][1], acc[cs][2], acc[cs][3]);
        *(float4*)(o + 4) = make_float4(acc[cs][4], acc[cs][5], acc[cs][6], acc[cs][7]);
    }
}

extern "C" void kernel_launch(void* const* d_in, const int* in_sizes, int n_in,
                              void* d_out, int out_size, void* d_ws, size_t ws_size,
                              hipStream_t stream) {
    const float* x = (const float*)d_in[0];
    const float* w = (const float*)d_in[1];
    float* out     = (float*)d_out;

    dim3 grid(2048), block(256);
    hipLaunchKernelGGL(dil2d_kernel, grid, block, 0, stream, x, w, out);
}